// Round 3
// baseline (436.323 us; speedup 1.0000x reference)
//
#include <hip/hip_runtime.h>
#include <hip/hip_bf16.h>

#define DD 128
#define VOX (128 * 128 * 128)   // 2097152
#define P 130                   // padded dim
#define PP (P * P)              // 16900
#define PVOX (P * P * P)        // 2197000

typedef unsigned short u16;
typedef __attribute__((ext_vector_type(8))) short bf16x8;
typedef __attribute__((ext_vector_type(4))) float f32x4;
typedef __attribute__((ext_vector_type(2))) float f32x2;

__device__ __forceinline__ u16 f2bf(float f) {
    unsigned int u = __float_as_uint(f);
    return (u16)((u + 0x7FFF + ((u >> 16) & 1)) >> 16);  // RNE
}
__device__ __forceinline__ float blo(unsigned u) { return __uint_as_float(u << 16); }
__device__ __forceinline__ float bhi(unsigned u) { return __uint_as_float(u & 0xffff0000u); }

// fast tanh: 1 - 2/(1+e^{2x}); exact at +-inf, ~1e-6 rel err
__device__ __forceinline__ float fast_tanh(float x) {
    float e = __expf(2.0f * x);
    return 1.0f - 2.0f * __builtin_amdgcn_rcpf(1.0f + e);
}

// prep: w2frag[(s*64+lane)*8+j] = bf16(w2[oc=lane&15][ic=j][tap=s*4+(lane>>4)]), 0 if tap>26
//       w3t[tap*16+ic] = w3[ic*27+tap]
__global__ __launch_bounds__(256) void prep_kernel(
    const float* __restrict__ w2, const float* __restrict__ w3,
    u16* __restrict__ w2frag, float* __restrict__ w3t) {
    int i = blockIdx.x * 256 + threadIdx.x;
    if (i < 3584) {
        int j = i & 7, l = (i >> 3) & 63, s = i >> 9;
        int tap = s * 4 + (l >> 4), oc = l & 15, ic = j;
        float v = (tap < 27) ? w2[(oc * 8 + ic) * 27 + tap] : 0.0f;
        w2frag[i] = f2bf(v);
    }
    if (i < 432) {
        int tap = i >> 4, ic = i & 15;
        w3t[i] = w3[ic * 27 + tap];
    }
}

// zero the halo shells of padded x1 (8ch) and x2 (16ch)
__global__ __launch_bounds__(256) void zero_halo_kernel(u16* __restrict__ x1,
                                                        u16* __restrict__ x2) {
    int i = blockIdx.x * 256 + threadIdx.x;
    if (i >= PVOX) return;
    int d = i / PP;
    int r = i - d * PP;
    int h = r / P;
    int w = r - h * P;
    if (d == 0 || d == P - 1 || h == 0 || h == P - 1 || w == 0 || w == P - 1) {
        uint4 z = {0u, 0u, 0u, 0u};
        *(uint4*)(x1 + (size_t)i * 8) = z;
        *(uint4*)(x2 + (size_t)i * 16) = z;
        *(uint4*)(x2 + (size_t)i * 16 + 8) = z;
    }
}

// conv1: in [128^3] fp32 (one batch), field fused, relu, out bf16 channels-last padded [130^3][8]
// 2 voxels (along w) per thread; all loads unconditional via clamped addresses + mult masks.
__global__ __launch_bounds__(256) void conv1_kernel(
    const float* __restrict__ in, const float* __restrict__ w1,
    const float* __restrict__ b1, u16* __restrict__ x1) {
    __shared__ float table[384];
    for (int s = threadIdx.x; s < 384; s += 256)
        table[s] = 1.0f + 0.1f * sinf(6.283185307179586f * (float)s / 384.0f);
    __syncthreads();

    const int t = blockIdx.x * 256 + threadIdx.x;  // VOX/2 threads
    const int w0 = (t & 63) * 2;
    const int h = (t >> 6) & 127;
    const int d = t >> 13;

    float acc0[8], acc1[8];
#pragma unroll
    for (int oc = 0; oc < 8; ++oc) { acc0[oc] = b1[oc]; acc1[oc] = b1[oc]; }

#pragma unroll
    for (int dz = 0; dz < 3; ++dz) {
        const int zz = d + dz - 1;
        const int zc = zz < 0 ? 0 : (zz > 127 ? 127 : zz);
        const bool zok = (unsigned)zz < 128u;
#pragma unroll
        for (int dy = 0; dy < 3; ++dy) {
            const int yy = h + dy - 1;
            const int yc = yy < 0 ? 0 : (yy > 127 ? 127 : yy);
            const bool rok = zok && ((unsigned)yy < 128u);
            const int rowbase = (zc * 128 + yc) * 128;
            const int sbase = zz + yy;
            float val[4];
#pragma unroll
            for (int i = 0; i < 4; ++i) {
                const int xa = w0 - 1 + i;
                const int xc = xa < 0 ? 0 : (xa > 127 ? 127 : xa);
                int si = sbase + xa;
                si = si < 0 ? 0 : (si > 381 ? 381 : si);
                const float m = (rok && ((unsigned)xa < 128u)) ? table[si] : 0.0f;
                val[i] = in[rowbase + xc] * m;
            }
#pragma unroll
            for (int dx = 0; dx < 3; ++dx) {
                const int tap = dz * 9 + dy * 3 + dx;
#pragma unroll
                for (int oc = 0; oc < 8; ++oc) {
                    const float wgt = w1[oc * 27 + tap];
                    acc0[oc] = fmaf(wgt, val[dx], acc0[oc]);
                    acc1[oc] = fmaf(wgt, val[dx + 1], acc1[oc]);
                }
            }
        }
    }
    const size_t elem = ((size_t)(d + 1) * P + (h + 1)) * P + (w0 + 1);
    uint4 o0, o1;
#define PK(a, b) (((unsigned)f2bf((a) > 0.f ? (a) : 0.f)) | (((unsigned)f2bf((b) > 0.f ? (b) : 0.f)) << 16))
    o0.x = PK(acc0[0], acc0[1]); o0.y = PK(acc0[2], acc0[3]);
    o0.z = PK(acc0[4], acc0[5]); o0.w = PK(acc0[6], acc0[7]);
    o1.x = PK(acc1[0], acc1[1]); o1.y = PK(acc1[2], acc1[3]);
    o1.z = PK(acc1[4], acc1[5]); o1.w = PK(acc1[6], acc1[7]);
#undef PK
    *(uint4*)(x1 + elem * 8) = o0;
    *(uint4*)(x1 + (elem + 1) * 8) = o1;
}

// conv2: implicit-GEMM MFMA, padded layouts, no boundary logic.
// One wave = one (d,h) row = 8 tiles of 16 voxels; 7 k-steps; 56 MFMAs/wave.
__global__ __launch_bounds__(256) void conv2_mfma_kernel(
    const u16* __restrict__ x1, const u16* __restrict__ w2frag,
    const float* __restrict__ b2, u16* __restrict__ x2) {
    const int lane = threadIdx.x & 63;
    const int row = blockIdx.x * 4 + (threadIdx.x >> 6);
    const int q = lane >> 4;
    const int mi = lane & 15;
    const int d0 = row >> 7;
    const int h0 = row & 127;

    f32x4 acc[8];
#pragma unroll
    for (int t = 0; t < 8; ++t) acc[t] = (f32x4){0.f, 0.f, 0.f, 0.f};

#pragma unroll
    for (int s = 0; s < 7; ++s) {
        int tap = s * 4 + q;
        if (tap > 26) tap = 26;  // pad tap: B-frag is zero there
        const int dz = tap / 9;
        const int rem = tap - dz * 9;
        const int dy = rem / 3;
        const int dx = rem - dy * 3;
        // voxel (d0+dz-1, h0+dy-1, 16t+mi+dx-1) -> padded elem offset (+1 cancels -1)
        const u16* ap = x1 + ((size_t)((d0 + dz) * P + (h0 + dy)) * P + (mi + dx)) * 8;
        const bf16x8 bf = *(const bf16x8*)(w2frag + (size_t)(s * 64 + lane) * 8);
#pragma unroll
        for (int t = 0; t < 8; ++t) {
            bf16x8 a = *(const bf16x8*)(ap + t * 128);  // +t*16 voxels
            acc[t] = __builtin_amdgcn_mfma_f32_16x16x32_bf16(a, bf, acc[t], 0, 0, 0);
        }
    }

    // C/D: col(oc)=mi, row(m)=q*4+r -> voxel w = 16t + q*4 + r
    const float bias = b2[mi];
    const size_t obase = ((size_t)(d0 + 1) * P + (h0 + 1)) * P + 1;
#pragma unroll
    for (int t = 0; t < 8; ++t) {
#pragma unroll
        for (int r = 0; r < 4; ++r) {
            float v = acc[t][r] + bias;
            v = v > 0.f ? v : 0.f;
            x2[(obase + 16 * t + q * 4 + r) * 16 + mi] = f2bf(v);
        }
    }
}

// conv3: padded x2 [130^3][16] bf16 -> out fp32 [128^3] (one batch), tanh.
// 4 voxels per thread; per (dz,dy) row: 6 chunk loads shared across 3 dx taps and 4 voxels.
__global__ __launch_bounds__(256) void conv3_kernel(
    const u16* __restrict__ x2, const float* __restrict__ w3t,
    const float* __restrict__ b3, float* __restrict__ out) {
    const int t = blockIdx.x * 256 + threadIdx.x;  // VOX/4 threads
    const int w0 = (t & 31) * 4;
    const int h = (t >> 5) & 127;
    const int d = t >> 12;

    f32x2 acc[4];
#pragma unroll
    for (int v = 0; v < 4; ++v) acc[v] = (f32x2){0.f, 0.f};

#pragma unroll
    for (int dz = 0; dz < 3; ++dz) {
#pragma unroll
        for (int dy = 0; dy < 3; ++dy) {
            // chunk c = voxel (d+dz-1, h+dy-1, w0-1+c) -> padded base at w0+c
            const u16* rowp = x2 + ((size_t)((d + dz) * P + (h + dy)) * P + w0) * 16;
            uint4 lo[6], hi[6];
#pragma unroll
            for (int c = 0; c < 6; ++c) {
                lo[c] = *(const uint4*)(rowp + c * 16);
                hi[c] = *(const uint4*)(rowp + c * 16 + 8);
            }
#pragma unroll
            for (int j = 0; j < 8; ++j) {  // channel pair (2j, 2j+1)
                f32x2 f[6];
#pragma unroll
                for (int c = 0; c < 6; ++c) {
                    const unsigned u = (j < 4) ? (&lo[c].x)[j] : (&hi[c].x)[j - 4];
                    f[c] = (f32x2){blo(u), bhi(u)};
                }
#pragma unroll
                for (int dx = 0; dx < 3; ++dx) {
                    const float* wp = w3t + (dz * 9 + dy * 3 + dx) * 16 + 2 * j;
                    const f32x2 wv = {wp[0], wp[1]};
#pragma unroll
                    for (int v = 0; v < 4; ++v)
                        acc[v] = __builtin_elementwise_fma(wv, f[v + dx], acc[v]);
                }
            }
        }
    }
    const float bias = b3[0];
    float4 o;
    o.x = fast_tanh(acc[0].x + acc[0].y + bias);
    o.y = fast_tanh(acc[1].x + acc[1].y + bias);
    o.z = fast_tanh(acc[2].x + acc[2].y + bias);
    o.w = fast_tanh(acc[3].x + acc[3].y + bias);
    *(float4*)(out + ((size_t)(d * 128 + h) * 128 + w0)) = o;
}

extern "C" void kernel_launch(void* const* d_in, const int* in_sizes, int n_in,
                              void* d_out, int out_size, void* d_ws, size_t ws_size,
                              hipStream_t stream) {
    const float* cube = (const float*)d_in[0];
    const float* w1 = (const float*)d_in[1];
    const float* b1 = (const float*)d_in[2];
    const float* w2 = (const float*)d_in[3];
    const float* b2 = (const float*)d_in[4];
    const float* w3 = (const float*)d_in[5];
    const float* b3 = (const float*)d_in[6];
    float* out = (float*)d_out;

    // ws: w2frag 7168B | w3t 1728B | (pad) | x1 padded 35.15MB | x2 padded 70.3MB
    char* ws = (char*)d_ws;
    u16* w2frag = (u16*)ws;
    float* w3t = (float*)(ws + 7168);
    u16* x1 = (u16*)(ws + 16384);
    u16* x2 = (u16*)(ws + 16384 + (size_t)PVOX * 8 * sizeof(u16));

    prep_kernel<<<dim3(14), dim3(256), 0, stream>>>(w2, w3, w2frag, w3t);
    zero_halo_kernel<<<dim3((PVOX + 255) / 256), dim3(256), 0, stream>>>(x1, x2);

    for (int b = 0; b < 2; ++b) {
        conv1_kernel<<<dim3(VOX / 2 / 256), dim3(256), 0, stream>>>(
            cube + (size_t)b * VOX, w1, b1, x1);
        conv2_mfma_kernel<<<dim3(128 * 128 / 4), dim3(256), 0, stream>>>(x1, w2frag, b2, x2);
        conv3_kernel<<<dim3(VOX / 4 / 256), dim3(256), 0, stream>>>(
            x2, w3t, b3, out + (size_t)b * VOX);
    }
}

// Round 4
// 326.680 us; speedup vs baseline: 1.3356x; 1.3356x over previous
//
#include <hip/hip_runtime.h>
#include <hip/hip_fp16.h>

#define VOX (128 * 128 * 128)   // 2097152
#define P 130                   // padded dim
#define PP (P * P)              // 16900
#define PVOX (P * P * P)        // 2197000

typedef unsigned short u16;
typedef _Float16 f16x2 __attribute__((ext_vector_type(2)));
typedef _Float16 f16x8 __attribute__((ext_vector_type(8)));
typedef __attribute__((ext_vector_type(4))) float f32x4;

__device__ __forceinline__ u16 f2h(float f) {
    return __builtin_bit_cast(unsigned short, (_Float16)f);
}
__device__ __forceinline__ unsigned pkh_relu(float a, float b) {
    float ra = a > 0.f ? a : 0.f, rb = b > 0.f ? b : 0.f;
    return (unsigned)f2h(ra) | ((unsigned)f2h(rb) << 16);
}
__device__ __forceinline__ f16x2 h2(unsigned u) { return __builtin_bit_cast(f16x2, u); }

// dot2: acc += a.x*b.x + a.y*b.y  (f32 accumulate, single V_DOT2_F32_F16)
__device__ __forceinline__ float dot2(unsigned a, unsigned b, float c) {
#if __has_builtin(__builtin_amdgcn_fdot2)
    return __builtin_amdgcn_fdot2(h2(a), h2(b), c, false);
#else
    f16x2 av = h2(a), bv = h2(b);
    c = fmaf((float)av.x, (float)bv.x, c);
    return fmaf((float)av.y, (float)bv.y, c);
#endif
}

// fast tanh: 1 - 2/(1+e^{2x})
__device__ __forceinline__ float fast_tanh(float x) {
    float e = __expf(2.0f * x);
    return 1.0f - 2.0f * __builtin_amdgcn_rcpf(1.0f + e);
}

// prep: w2frag[(s*64+lane)*8+j] = f16(w2[oc=lane&15][ic=j][tap=s*4+(lane>>4)]), 0 if tap>26
//       w3p[tap*8+j] = packed f16 pair (w3[ic=2j][tap], w3[ic=2j+1][tap])
__global__ __launch_bounds__(256) void prep_kernel(
    const float* __restrict__ w2, const float* __restrict__ w3,
    u16* __restrict__ w2frag, unsigned* __restrict__ w3p) {
    int i = blockIdx.x * 256 + threadIdx.x;
    if (i < 3584) {
        int j = i & 7, l = (i >> 3) & 63, s = i >> 9;
        int tap = s * 4 + (l >> 4), oc = l & 15, ic = j;
        float v = (tap < 27) ? w2[(oc * 8 + ic) * 27 + tap] : 0.0f;
        w2frag[i] = f2h(v);
    }
    if (i < 216) {
        int tap = i >> 3, j = i & 7;
        w3p[i] = (unsigned)f2h(w3[(2 * j) * 27 + tap]) |
                 ((unsigned)f2h(w3[(2 * j + 1) * 27 + tap]) << 16);
    }
}

// zero the halo shells of padded x1 (8ch) and x2 (16ch)
__global__ __launch_bounds__(256) void zero_halo_kernel(u16* __restrict__ x1,
                                                        u16* __restrict__ x2) {
    int i = blockIdx.x * 256 + threadIdx.x;
    if (i >= PVOX) return;
    int d = i / PP;
    int r = i - d * PP;
    int h = r / P;
    int w = r - h * P;
    if (d == 0 || d == P - 1 || h == 0 || h == P - 1 || w == 0 || w == P - 1) {
        uint4 z = {0u, 0u, 0u, 0u};
        *(uint4*)(x1 + (size_t)i * 8) = z;
        *(uint4*)(x2 + (size_t)i * 16) = z;
        *(uint4*)(x2 + (size_t)i * 16 + 8) = z;
    }
}

// conv1: in [128^3] fp32 (one batch), field fused, relu, out f16 channels-last padded [130^3][8]
__global__ __launch_bounds__(256) void conv1_kernel(
    const float* __restrict__ in, const float* __restrict__ w1,
    const float* __restrict__ b1, u16* __restrict__ x1) {
    __shared__ float table[384];
    for (int s = threadIdx.x; s < 384; s += 256)
        table[s] = 1.0f + 0.1f * sinf(6.283185307179586f * (float)s / 384.0f);
    __syncthreads();

    const int t = blockIdx.x * 256 + threadIdx.x;  // VOX/2 threads
    const int w0 = (t & 63) * 2;
    const int h = (t >> 6) & 127;
    const int d = t >> 13;

    float acc0[8], acc1[8];
#pragma unroll
    for (int oc = 0; oc < 8; ++oc) { acc0[oc] = b1[oc]; acc1[oc] = b1[oc]; }

#pragma unroll
    for (int dz = 0; dz < 3; ++dz) {
        const int zz = d + dz - 1;
        const int zc = zz < 0 ? 0 : (zz > 127 ? 127 : zz);
        const bool zok = (unsigned)zz < 128u;
#pragma unroll
        for (int dy = 0; dy < 3; ++dy) {
            const int yy = h + dy - 1;
            const int yc = yy < 0 ? 0 : (yy > 127 ? 127 : yy);
            const bool rok = zok && ((unsigned)yy < 128u);
            const int rowbase = (zc * 128 + yc) * 128;
            const int sbase = zz + yy;
            float val[4];
#pragma unroll
            for (int i = 0; i < 4; ++i) {
                const int xa = w0 - 1 + i;
                const int xc = xa < 0 ? 0 : (xa > 127 ? 127 : xa);
                int si = sbase + xa;
                si = si < 0 ? 0 : (si > 381 ? 381 : si);
                const float m = (rok && ((unsigned)xa < 128u)) ? table[si] : 0.0f;
                val[i] = in[rowbase + xc] * m;
            }
#pragma unroll
            for (int dx = 0; dx < 3; ++dx) {
                const int tap = dz * 9 + dy * 3 + dx;
#pragma unroll
                for (int oc = 0; oc < 8; ++oc) {
                    const float wgt = w1[oc * 27 + tap];
                    acc0[oc] = fmaf(wgt, val[dx], acc0[oc]);
                    acc1[oc] = fmaf(wgt, val[dx + 1], acc1[oc]);
                }
            }
        }
    }
    const size_t elem = ((size_t)(d + 1) * P + (h + 1)) * P + (w0 + 1);
    uint4 o0, o1;
    o0.x = pkh_relu(acc0[0], acc0[1]); o0.y = pkh_relu(acc0[2], acc0[3]);
    o0.z = pkh_relu(acc0[4], acc0[5]); o0.w = pkh_relu(acc0[6], acc0[7]);
    o1.x = pkh_relu(acc1[0], acc1[1]); o1.y = pkh_relu(acc1[2], acc1[3]);
    o1.z = pkh_relu(acc1[4], acc1[5]); o1.w = pkh_relu(acc1[6], acc1[7]);
    *(uint4*)(x1 + elem * 8) = o0;
    *(uint4*)(x1 + (elem + 1) * 8) = o1;
}

// conv2: implicit-GEMM MFMA (f16), padded layouts, no boundary logic.
// One wave = one (d,h) row = 8 tiles of 16 voxels; 7 k-steps; 56 MFMAs/wave.
__global__ __launch_bounds__(256) void conv2_mfma_kernel(
    const u16* __restrict__ x1, const u16* __restrict__ w2frag,
    const float* __restrict__ b2, u16* __restrict__ x2) {
    const int lane = threadIdx.x & 63;
    const int row = blockIdx.x * 4 + (threadIdx.x >> 6);
    const int q = lane >> 4;
    const int mi = lane & 15;
    const int d0 = row >> 7;
    const int h0 = row & 127;

    f32x4 acc[8];
#pragma unroll
    for (int t = 0; t < 8; ++t) acc[t] = (f32x4){0.f, 0.f, 0.f, 0.f};

#pragma unroll
    for (int s = 0; s < 7; ++s) {
        int tap = s * 4 + q;
        if (tap > 26) tap = 26;  // pad tap: B-frag is zero there
        const int dz = tap / 9;
        const int rem = tap - dz * 9;
        const int dy = rem / 3;
        const int dx = rem - dy * 3;
        const u16* ap = x1 + ((size_t)((d0 + dz) * P + (h0 + dy)) * P + (mi + dx)) * 8;
        const f16x8 bf = *(const f16x8*)(w2frag + (size_t)(s * 64 + lane) * 8);
#pragma unroll
        for (int t = 0; t < 8; ++t) {
            f16x8 a = *(const f16x8*)(ap + t * 128);  // +t*16 voxels
            acc[t] = __builtin_amdgcn_mfma_f32_16x16x32_f16(a, bf, acc[t], 0, 0, 0);
        }
    }

    // C/D: col(oc)=mi, row(m)=q*4+r -> voxel w = 16t + q*4 + r
    const float bias = b2[mi];
    const size_t obase = ((size_t)(d0 + 1) * P + (h0 + 1)) * P + 1;
#pragma unroll
    for (int t = 0; t < 8; ++t) {
#pragma unroll
        for (int r = 0; r < 4; ++r) {
            float v = acc[t][r] + bias;
            v = v > 0.f ? v : 0.f;
            x2[(obase + 16 * t + q * 4 + r) * 16 + mi] = f2h(v);
        }
    }
}

// conv3: padded x2 [130^3][16] f16 -> out fp32 [128^3] (one batch), tanh.
// 1 voxel/thread; per tap: 2 b128 loads + 8 fdot2 (no unpack).
__global__ __launch_bounds__(256) void conv3_kernel(
    const u16* __restrict__ x2, const unsigned* __restrict__ w3p,
    const float* __restrict__ b3, float* __restrict__ out) {
    const int t = blockIdx.x * 256 + threadIdx.x;  // VOX threads
    const int w = t & 127;
    const int h = (t >> 7) & 127;
    const int d = t >> 14;

    float a0 = 0.f, a1 = 0.f, a2 = 0.f, a3 = 0.f;

#pragma unroll
    for (int dz = 0; dz < 3; ++dz) {
#pragma unroll
        for (int dy = 0; dy < 3; ++dy) {
            // padded base: voxel (d+dz-1, h+dy-1, w-1) -> padded idx (d+dz, h+dy, w)
            const u16* rp = x2 + ((size_t)((d + dz) * P + (h + dy)) * P + w) * 16;
#pragma unroll
            for (int dx = 0; dx < 3; ++dx) {
                const uint4 lo = *(const uint4*)(rp + dx * 16);
                const uint4 hi = *(const uint4*)(rp + dx * 16 + 8);
                const unsigned* wp = w3p + (dz * 9 + dy * 3 + dx) * 8;
                a0 = dot2(lo.x, wp[0], a0);
                a1 = dot2(lo.y, wp[1], a1);
                a2 = dot2(lo.z, wp[2], a2);
                a3 = dot2(lo.w, wp[3], a3);
                a0 = dot2(hi.x, wp[4], a0);
                a1 = dot2(hi.y, wp[5], a1);
                a2 = dot2(hi.z, wp[6], a2);
                a3 = dot2(hi.w, wp[7], a3);
            }
        }
    }
    out[(size_t)(d * 128 + h) * 128 + w] = fast_tanh((a0 + a1) + (a2 + a3) + b3[0]);
}

extern "C" void kernel_launch(void* const* d_in, const int* in_sizes, int n_in,
                              void* d_out, int out_size, void* d_ws, size_t ws_size,
                              hipStream_t stream) {
    const float* cube = (const float*)d_in[0];
    const float* w1 = (const float*)d_in[1];
    const float* b1 = (const float*)d_in[2];
    const float* w2 = (const float*)d_in[3];
    const float* b2 = (const float*)d_in[4];
    const float* w3 = (const float*)d_in[5];
    const float* b3 = (const float*)d_in[6];
    float* out = (float*)d_out;

    // ws: w2frag 7168B | w3p 864B | (pad to 16KiB) | x1 padded f16 [PVOX][8] | x2 padded f16 [PVOX][16]
    char* ws = (char*)d_ws;
    u16* w2frag = (u16*)ws;
    unsigned* w3p = (unsigned*)(ws + 7168);
    u16* x1 = (u16*)(ws + 16384);
    u16* x2 = (u16*)(ws + 16384 + (size_t)PVOX * 8 * sizeof(u16));

    prep_kernel<<<dim3(14), dim3(256), 0, stream>>>(w2, w3, w2frag, w3p);
    zero_halo_kernel<<<dim3((PVOX + 255) / 256), dim3(256), 0, stream>>>(x1, x2);

    for (int b = 0; b < 2; ++b) {
        conv1_kernel<<<dim3(VOX / 2 / 256), dim3(256), 0, stream>>>(
            cube + (size_t)b * VOX, w1, b1, x1);
        conv2_mfma_kernel<<<dim3(128 * 128 / 4), dim3(256), 0, stream>>>(x1, w2frag, b2, x2);
        conv3_kernel<<<dim3(VOX / 256), dim3(256), 0, stream>>>(
            x2, w3p, b3, out + (size_t)b * VOX);
    }
}